// Round 1
// baseline (32500.644 us; speedup 1.0000x reference)
//
#include <hip/hip_runtime.h>
#include <hip/hip_bf16.h>

// LSTM: B=128, T=2048, H=256, gates=1024, in=82 (one-hot 64 + one-hot 16 + rw + dn)
// Strategy: 8 persistent WGs x 1024 threads; WG owns 16 batch rows for all 2048 steps.
// W_hh and W_ih live in registers as bf16 MFMA B-fragments. Input projection fused
// as 3 extra K-tiles with one-hot A-fragments built in-register. One barrier/step,
// h passes between steps via double-buffered LDS tile.

namespace {

constexpr int Tt   = 2048;
constexpr int Hh   = 256;
constexpr int NBat = 16;    // batch rows per WG
constexpr int LDP  = 264;   // padded LDS row stride in bf16 elems (breaks bank conflicts)
constexpr int INED = 82;

typedef __attribute__((ext_vector_type(8))) short short8;   // 8 bf16 = 4 VGPRs
typedef __attribute__((ext_vector_type(4))) float float4v;  // MFMA C/D frag

__device__ inline short bf16cvt(float f) {
  unsigned u = __float_as_uint(f);
  unsigned r = (u + 0x7FFFu + ((u >> 16) & 1u)) >> 16;  // RNE
  return (short)r;
}
__device__ inline float sigf(float x) {
  // 1/(1+2^(-x*log2e)); saturates safely at +-inf
  float e = __builtin_amdgcn_exp2f(-1.4426950408889634f * x);
  return __builtin_amdgcn_rcpf(1.0f + e);
}
__device__ inline float tanhf_fast(float x) {
  float ax = __builtin_fabsf(x);
  float e  = __builtin_amdgcn_exp2f(-2.8853900817779268f * ax);  // 2^(-2|x|*log2e)
  float r  = (1.0f - e) * __builtin_amdgcn_rcpf(1.0f + e);
  return __builtin_copysignf(r, x);
}

__global__ __launch_bounds__(1024, 4) void lstm_fused(
    const int*   __restrict__ xs,     // (B,T) state ids
    const float* __restrict__ hidden, // (B, 2H) [h0 | c0]
    const int*   __restrict__ pa,     // (B,T) prev_action
    const float* __restrict__ prw,    // (B,T) prev_reward
    const float* __restrict__ pdn,    // (B,T) prev_done
    const float* __restrict__ Wih,    // (4H, 82)
    const float* __restrict__ Whh,    // (4H, H)
    const float* __restrict__ bih,    // (4H)
    const float* __restrict__ bhh,    // (4H)
    float*       __restrict__ out)    // features (B,T,H) then final_hidden (B,2H)
{
  __shared__ alignas(16) short hbuf[2][NBat * LDP];

  const int tid = threadIdx.x;
  const int w   = tid >> 6;    // wave 0..15; owns j-tile = w
  const int l   = tid & 63;
  const int lm  = l & 15;      // A-frag row (batch m) / B,C col
  const int lq  = l >> 4;      // lane quad
  const int b0  = blockIdx.x * NBat;

  // ---- W_hh B-fragments: 4 gate classes (p) x 8 K-tiles, in registers ----
  // B[k][n] = Whh[g][k], g = 256*p + 16*w + lm ; frag elem j <-> k = 32*kst + 8*lq + j
  short8 bhhf[4][8];
  #pragma unroll
  for (int p = 0; p < 4; ++p) {
    const int g = 256 * p + 16 * w + lm;
    const float* row = Whh + (size_t)g * Hh;
    #pragma unroll
    for (int kst = 0; kst < 8; ++kst) {
      const int k0 = kst * 32 + lq * 8;
      const float4v f0 = *reinterpret_cast<const float4v*>(row + k0);
      const float4v f1 = *reinterpret_cast<const float4v*>(row + k0 + 4);
      short8 v;
      v[0] = bf16cvt(f0[0]); v[1] = bf16cvt(f0[1]); v[2] = bf16cvt(f0[2]); v[3] = bf16cvt(f0[3]);
      v[4] = bf16cvt(f1[0]); v[5] = bf16cvt(f1[1]); v[6] = bf16cvt(f1[2]); v[7] = bf16cvt(f1[3]);
      bhhf[p][kst] = v;
    }
  }

  // ---- W_ih B-fragments: 3 K-tiles covering k in [0,96), valid k < 82 ----
  short8 bihf[4][3];
  #pragma unroll
  for (int p = 0; p < 4; ++p) {
    const int g = 256 * p + 16 * w + lm;
    const float* row = Wih + (size_t)g * INED;
    #pragma unroll
    for (int ks = 0; ks < 3; ++ks) {
      short8 v;
      #pragma unroll
      for (int jj = 0; jj < 8; ++jj) {
        const int k = ks * 32 + lq * 8 + jj;
        v[jj] = (k < INED) ? bf16cvt(row[k]) : (short)0;
      }
      bihf[p][ks] = v;
    }
  }

  // ---- bias (b_ih + b_hh) per gate class, and c-state init ----
  const int j = 16 * w + lm;  // this lane's hidden-unit column
  float bs[4];
  #pragma unroll
  for (int p = 0; p < 4; ++p) {
    const int g = 256 * p + j;
    bs[p] = bih[g] + bhh[g];
  }
  float cst[4], hlast[4];
  #pragma unroll
  for (int r = 0; r < 4; ++r) {
    const int m = lq * 4 + r;
    cst[r]   = hidden[(size_t)(b0 + m) * (2 * Hh) + Hh + j];
    hlast[r] = 0.0f;
  }

  // ---- stage h(-1) into hbuf[1] (step 0 reads parity (0+1)&1 = 1) ----
  for (int v = tid; v < NBat * Hh; v += 1024) {
    const int m = v >> 8, k = v & (Hh - 1);
    hbuf[1][m * LDP + k] = bf16cvt(hidden[(size_t)(b0 + m) * (2 * Hh) + k]);
  }
  __syncthreads();

  const int xrow = (b0 + lm) * Tt;  // per-lane scalar-feature row (batch lm)

  for (int t = 0; t < Tt; ++t) {
    // scalar features for this step (issued early; consumed after Whh MFMAs)
    const int   xv  = xs[xrow + t];
    const int   av  = pa[xrow + t];
    const short rwb = bf16cvt(prw[xrow + t]);
    const short dnb = bf16cvt(pdn[xrow + t]);

    const short* hb = hbuf[(t + 1) & 1];
    float4v acc[4];
    #pragma unroll
    for (int p = 0; p < 4; ++p) acc[p] = float4v{0.f, 0.f, 0.f, 0.f};

    // recurrent part: K = 256 over 8 K-tiles, A from LDS
    #pragma unroll
    for (int kst = 0; kst < 8; ++kst) {
      const short8 af = *reinterpret_cast<const short8*>(hb + lm * LDP + kst * 32 + lq * 8);
      #pragma unroll
      for (int p = 0; p < 4; ++p)
        acc[p] = __builtin_amdgcn_mfma_f32_16x16x32_bf16(af, bhhf[p][kst], acc[p], 0, 0, 0);
    }

    // input projection part: 3 K-tiles of one-hot features built in-register
    #pragma unroll
    for (int ks = 0; ks < 3; ++ks) {
      short8 af;
      #pragma unroll
      for (int jj = 0; jj < 8; ++jj) {
        const int kk = ks * 32 + lq * 8 + jj;
        short v = ((kk == xv) || (kk == 64 + av)) ? (short)0x3F80 : (short)0;
        if (kk == 80) v = rwb;
        if (kk == 81) v = dnb;
        af[jj] = v;
      }
      #pragma unroll
      for (int p = 0; p < 4; ++p)
        acc[p] = __builtin_amdgcn_mfma_f32_16x16x32_bf16(af, bihf[p][ks], acc[p], 0, 0, 0);
    }

    // gate nonlinearities + state update; lane holds rows m = 4*lq + r, col j
    short* hw = hbuf[t & 1];
    #pragma unroll
    for (int r = 0; r < 4; ++r) {
      const float iv = acc[0][r] + bs[0];
      const float fv = acc[1][r] + bs[1];
      const float gv = acc[2][r] + bs[2];
      const float ov = acc[3][r] + bs[3];
      const float c  = sigf(fv) * cst[r] + sigf(iv) * tanhf_fast(gv);
      cst[r] = c;
      const float hn = sigf(ov) * tanhf_fast(c);
      hlast[r] = hn;
      const int m = lq * 4 + r;
      out[((size_t)(b0 + m) * Tt + t) * Hh + j] = hn;   // features
      hw[m * LDP + j] = bf16cvt(hn);                    // h for next step
    }
    __syncthreads();
  }

  // ---- final_hidden = [hT | cT], appended after features ----
  const size_t base = (size_t)128 * Tt * Hh;
  #pragma unroll
  for (int r = 0; r < 4; ++r) {
    const int m = lq * 4 + r;
    out[base + (size_t)(b0 + m) * (2 * Hh) + j]      = hlast[r];
    out[base + (size_t)(b0 + m) * (2 * Hh) + Hh + j] = cst[r];
  }
}

}  // namespace

extern "C" void kernel_launch(void* const* d_in, const int* in_sizes, int n_in,
                              void* d_out, int out_size, void* d_ws, size_t ws_size,
                              hipStream_t stream) {
  const int*   xs     = (const int*)  d_in[0];
  const float* hidden = (const float*)d_in[1];
  const int*   pa     = (const int*)  d_in[2];
  const float* prw    = (const float*)d_in[3];
  const float* pdn    = (const float*)d_in[4];
  const float* Wih    = (const float*)d_in[5];
  const float* Whh    = (const float*)d_in[6];
  const float* bih    = (const float*)d_in[7];
  const float* bhh    = (const float*)d_in[8];
  float* out = (float*)d_out;

  lstm_fused<<<dim3(8), dim3(1024), 0, stream>>>(
      xs, hidden, pa, prw, pdn, Wih, Whh, bih, bhh, out);
}

// Round 2
// 16666.179 us; speedup vs baseline: 1.9501x; 1.9501x over previous
//
#include <hip/hip_runtime.h>
#include <hip/hip_bf16.h>

// LSTM B=128,T=2048,H=256. Three-kernel plan:
//  prep:  transpose Wih -> WihT (fp32), bias sum, convert Whh classes g,o to bf16
//         MFMA B-fragments in ws ("obf").
//  xp:    precompute x_proj (one-hot gather) + biases for all (t,b,gate) as bf16
//         into ws (512 MB). Fully parallel, ~write-BW bound.
//  rec:   8 persistent WGs x 1024 thr; 16 batch rows/WG; classes i,f resident in
//         regs (64 VGPR/wave), class g kst0-1 in LDS, rest streamed from L2-resident
//         bf16 frags. One barrier/step. xp read per step as 16 ushorts/lane.

namespace {

constexpr int Tt   = 2048;
constexpr int Bb   = 128;
constexpr int Hh   = 256;
constexpr int NBat = 16;
constexpr int LDP  = 264;
constexpr int INED = 82;

constexpr size_t XP_OFF    = 0;
constexpr size_t XP_BYTES  = (size_t)Bb * Tt * 1024 * 2;          // 536870912
constexpr size_t WIHT_OFF  = XP_OFF + XP_BYTES;
constexpr size_t WIHT_BYTES= (size_t)84 * 1024 * 4;
constexpr size_t BSUM_OFF  = WIHT_OFF + WIHT_BYTES;
constexpr size_t BSUM_BYTES= 1024 * 4;
constexpr size_t OBF_OFF   = BSUM_OFF + BSUM_BYTES;
constexpr size_t OBF_BYTES = (size_t)2 * 16 * 8 * 64 * 16;        // 262144
constexpr size_t WS_NEED   = OBF_OFF + OBF_BYTES;

typedef __attribute__((ext_vector_type(8))) short short8;
typedef __attribute__((ext_vector_type(4))) float float4v;
typedef __attribute__((ext_vector_type(4))) unsigned short us4;

__device__ inline unsigned short bf16u(float f) {
  unsigned u = __float_as_uint(f);
  unsigned r = (u + 0x7FFFu + ((u >> 16) & 1u)) >> 16;  // RNE
  return (unsigned short)r;
}
__device__ inline float u2f(unsigned short u) {
  return __uint_as_float(((unsigned)u) << 16);
}
__device__ inline float sigf(float x) {
  float e = __builtin_amdgcn_exp2f(-1.4426950408889634f * x);
  return __builtin_amdgcn_rcpf(1.0f + e);
}
__device__ inline float tanhf_fast(float x) {
  float ax = __builtin_fabsf(x);
  float e  = __builtin_amdgcn_exp2f(-2.8853900817779268f * ax);
  float r  = (1.0f - e) * __builtin_amdgcn_rcpf(1.0f + e);
  return __builtin_copysignf(r, x);
}

// ---------------- prep: WihT, bias sum, Whh g/o bf16 fragments ----------------
__global__ __launch_bounds__(256) void prep_kernel(
    const float* __restrict__ Wih, const float* __restrict__ Whh,
    const float* __restrict__ bih, const float* __restrict__ bhh,
    unsigned char* __restrict__ ws)
{
  float*  WihT = (float*)(ws + WIHT_OFF);
  float*  bsum = (float*)(ws + BSUM_OFF);
  unsigned short* obf = (unsigned short*)(ws + OBF_OFF);
  const int T1 = 82 * 1024, T2 = 1024, T3 = 2 * 16 * 8 * 64;
  int id = blockIdx.x * 256 + threadIdx.x;
  if (id < T1) {
    int k = id >> 10, g = id & 1023;
    WihT[k * 1024 + g] = Wih[(size_t)g * INED + k];
  } else if (id < T1 + T2) {
    int g = id - T1;
    bsum[g] = bih[g] + bhh[g];
  } else if (id < T1 + T2 + T3) {
    int id3 = id - T1 - T2;
    int l = id3 & 63, kst = (id3 >> 6) & 7, w = (id3 >> 9) & 15, c = id3 >> 13;
    int lm = l & 15, lq = l >> 4;
    int row = 512 + 256 * c + 16 * w + lm;        // class g rows [512,768), o rows [768,1024)
    int k0  = kst * 32 + lq * 8;
    const float* src = Whh + (size_t)row * Hh + k0;
    unsigned short* dst = obf + (size_t)id3 * 8;
    #pragma unroll
    for (int j = 0; j < 8; ++j) dst[j] = bf16u(src[j]);
  }
}

// ---------------- xp: x_proj + biases, bf16, layout [t][b][g] ----------------
__global__ __launch_bounds__(256) void xp_kernel(
    const int* __restrict__ xs, const int* __restrict__ pa,
    const float* __restrict__ prw, const float* __restrict__ pdn,
    unsigned char* __restrict__ ws)
{
  const float* WihT = (const float*)(ws + WIHT_OFF);
  const float* bsum = (const float*)(ws + BSUM_OFF);
  unsigned short* xp = (unsigned short*)(ws + XP_OFF);
  const int t  = blockIdx.x;
  const int g4 = threadIdx.x * 4;

  const float4v w80 = *(const float4v*)(WihT + 80 * 1024 + g4);
  const float4v w81 = *(const float4v*)(WihT + 81 * 1024 + g4);
  const float4v bs  = *(const float4v*)(bsum + g4);

  for (int b = 0; b < Bb; ++b) {
    const int   xv = xs[(size_t)b * Tt + t];
    const int   av = pa[(size_t)b * Tt + t];
    const float rw = prw[(size_t)b * Tt + t];
    const float dn = pdn[(size_t)b * Tt + t];
    const float4v a = *(const float4v*)(WihT + (size_t)xv * 1024 + g4);
    const float4v c = *(const float4v*)(WihT + (size_t)(64 + av) * 1024 + g4);
    float4v v = a + c + rw * w80 + dn * w81 + bs;
    us4 p;
    p[0] = bf16u(v[0]); p[1] = bf16u(v[1]); p[2] = bf16u(v[2]); p[3] = bf16u(v[3]);
    *(us4*)(xp + ((size_t)t * Bb + b) * 1024 + g4) = p;
  }
}

// ---------------- recurrent kernel ----------------
__global__ __launch_bounds__(1024, 4) void lstm_rec(
    const float* __restrict__ hidden, const float* __restrict__ Whh,
    const unsigned char* __restrict__ ws, float* __restrict__ out)
{
  __shared__ alignas(16) short hbuf[2][NBat * LDP];      // 16.9 KB
  __shared__ alignas(16) short gfrag[2][16 * 64 * 8];    // class g, kst 0..1: 32 KB

  const unsigned short* xp  = (const unsigned short*)(ws + XP_OFF);
  const unsigned short* obf = (const unsigned short*)(ws + OBF_OFF);

  const int tid = threadIdx.x;
  const int w   = tid >> 6;
  const int l   = tid & 63;
  const int lm  = l & 15;
  const int lq  = l >> 4;
  const int b0  = blockIdx.x * NBat;
  const int j   = 16 * w + lm;

  // resident B-frags: classes i (rows [0,256)) and f (rows [256,512))
  short8 bif[2][8];
  #pragma unroll
  for (int p = 0; p < 2; ++p) {
    const float* row = Whh + (size_t)(256 * p + j) * Hh;
    #pragma unroll
    for (int kst = 0; kst < 8; ++kst) {
      const int k0 = kst * 32 + lq * 8;
      short8 v;
      #pragma unroll
      for (int jj = 0; jj < 8; ++jj) v[jj] = (short)bf16u(row[k0 + jj]);
      bif[p][kst] = v;
    }
  }
  // class-g kst 0..1 into LDS (each thread writes its own frag)
  {
    const float* row = Whh + (size_t)(512 + j) * Hh;
    #pragma unroll
    for (int kst = 0; kst < 2; ++kst) {
      const int k0 = kst * 32 + lq * 8;
      short8 v;
      #pragma unroll
      for (int jj = 0; jj < 8; ++jj) v[jj] = (short)bf16u(row[k0 + jj]);
      *(short8*)&gfrag[kst][(w * 64 + l) * 8] = v;
    }
  }

  // c-state init
  float cst[4];
  #pragma unroll
  for (int r = 0; r < 4; ++r)
    cst[r] = hidden[(size_t)(b0 + lq * 4 + r) * (2 * Hh) + Hh + j];

  // stage h(-1) into hbuf[1]
  for (int v = tid; v < NBat * Hh; v += 1024) {
    const int m = v >> 8, k = v & (Hh - 1);
    hbuf[1][m * LDP + k] = (short)bf16u(hidden[(size_t)(b0 + m) * (2 * Hh) + k]);
  }
  __syncthreads();

  for (int t = 0; t < Tt; ++t) {
    // xp loads: 16 ushorts (p x r), issued early
    unsigned short xpu[16];
    {
      const size_t base = ((size_t)t * Bb + b0 + lq * 4) * 1024 + j;
      #pragma unroll
      for (int p = 0; p < 4; ++p)
        #pragma unroll
        for (int r = 0; r < 4; ++r)
          xpu[p * 4 + r] = xp[base + (size_t)r * 1024 + p * 256];
    }

    const short* hb = hbuf[(t + 1) & 1];
    float4v acc[4];
    #pragma unroll
    for (int p = 0; p < 4; ++p) acc[p] = float4v{0.f, 0.f, 0.f, 0.f};

    #pragma unroll
    for (int kst = 0; kst < 8; ++kst) {
      const short8 af = *(const short8*)(hb + lm * LDP + kst * 32 + lq * 8);
      acc[0] = __builtin_amdgcn_mfma_f32_16x16x32_bf16(af, bif[0][kst], acc[0], 0, 0, 0);
      acc[1] = __builtin_amdgcn_mfma_f32_16x16x32_bf16(af, bif[1][kst], acc[1], 0, 0, 0);
      short8 gf;
      if (kst < 2) gf = *(const short8*)&gfrag[kst][(w * 64 + l) * 8];
      else         gf = *(const short8*)(obf + (size_t)(((0 * 16 + w) * 8 + kst) * 64 + l) * 8);
      acc[2] = __builtin_amdgcn_mfma_f32_16x16x32_bf16(af, gf, acc[2], 0, 0, 0);
      const short8 of = *(const short8*)(obf + (size_t)(((16 + w) * 8 + kst) * 64 + l) * 8);
      acc[3] = __builtin_amdgcn_mfma_f32_16x16x32_bf16(af, of, acc[3], 0, 0, 0);
    }

    short* hw = hbuf[t & 1];
    #pragma unroll
    for (int r = 0; r < 4; ++r) {
      const float iv = acc[0][r] + u2f(xpu[0 * 4 + r]);
      const float fv = acc[1][r] + u2f(xpu[1 * 4 + r]);
      const float gv = acc[2][r] + u2f(xpu[2 * 4 + r]);
      const float ov = acc[3][r] + u2f(xpu[3 * 4 + r]);
      const float c  = sigf(fv) * cst[r] + sigf(iv) * tanhf_fast(gv);
      cst[r] = c;
      const float hn = sigf(ov) * tanhf_fast(c);
      const int m = lq * 4 + r;
      out[((size_t)(b0 + m) * Tt + t) * Hh + j] = hn;
      hw[m * LDP + j] = (short)bf16u(hn);
    }
    __syncthreads();
  }

  // final_hidden = [hT | cT]; hT read back (bf16-rounded) from hbuf[1]
  const size_t base = (size_t)Bb * Tt * Hh;
  #pragma unroll
  for (int r = 0; r < 4; ++r) {
    const int m = lq * 4 + r;
    const float hT = u2f((unsigned short)hbuf[1][m * LDP + j]);
    out[base + (size_t)(b0 + m) * (2 * Hh) + j]      = hT;
    out[base + (size_t)(b0 + m) * (2 * Hh) + Hh + j] = cst[r];
  }
}

// ---------------- fallback (R1 kernel, known-correct, slow) ----------------
__global__ __launch_bounds__(1024, 4) void lstm_fused(
    const int* __restrict__ xs, const float* __restrict__ hidden,
    const int* __restrict__ pa, const float* __restrict__ prw,
    const float* __restrict__ pdn, const float* __restrict__ Wih,
    const float* __restrict__ Whh, const float* __restrict__ bih,
    const float* __restrict__ bhh, float* __restrict__ out)
{
  __shared__ alignas(16) short hbuf[2][NBat * LDP];
  const int tid = threadIdx.x;
  const int w = tid >> 6, l = tid & 63, lm = l & 15, lq = l >> 4;
  const int b0 = blockIdx.x * NBat;
  short8 bhhf[4][8];
  #pragma unroll
  for (int p = 0; p < 4; ++p) {
    const float* row = Whh + (size_t)(256 * p + 16 * w + lm) * Hh;
    #pragma unroll
    for (int kst = 0; kst < 8; ++kst) {
      short8 v;
      #pragma unroll
      for (int jj = 0; jj < 8; ++jj) v[jj] = (short)bf16u(row[kst * 32 + lq * 8 + jj]);
      bhhf[p][kst] = v;
    }
  }
  short8 bihf[4][3];
  #pragma unroll
  for (int p = 0; p < 4; ++p) {
    const float* row = Wih + (size_t)(256 * p + 16 * w + lm) * INED;
    #pragma unroll
    for (int ks = 0; ks < 3; ++ks) {
      short8 v;
      #pragma unroll
      for (int jj = 0; jj < 8; ++jj) {
        const int k = ks * 32 + lq * 8 + jj;
        v[jj] = (k < INED) ? (short)bf16u(row[k]) : (short)0;
      }
      bihf[p][ks] = v;
    }
  }
  const int j = 16 * w + lm;
  float bs[4];
  #pragma unroll
  for (int p = 0; p < 4; ++p) bs[p] = bih[256 * p + j] + bhh[256 * p + j];
  float cst[4], hlast[4];
  #pragma unroll
  for (int r = 0; r < 4; ++r) {
    cst[r] = hidden[(size_t)(b0 + lq * 4 + r) * (2 * Hh) + Hh + j];
    hlast[r] = 0.f;
  }
  for (int v = tid; v < NBat * Hh; v += 1024) {
    const int m = v >> 8, k = v & (Hh - 1);
    hbuf[1][m * LDP + k] = (short)bf16u(hidden[(size_t)(b0 + m) * (2 * Hh) + k]);
  }
  __syncthreads();
  const int xrow = (b0 + lm) * Tt;
  for (int t = 0; t < Tt; ++t) {
    const int xv = xs[xrow + t], av = pa[xrow + t];
    const unsigned short rwb = bf16u(prw[xrow + t]), dnb = bf16u(pdn[xrow + t]);
    const short* hb = hbuf[(t + 1) & 1];
    float4v acc[4];
    #pragma unroll
    for (int p = 0; p < 4; ++p) acc[p] = float4v{0.f, 0.f, 0.f, 0.f};
    #pragma unroll
    for (int kst = 0; kst < 8; ++kst) {
      const short8 af = *(const short8*)(hb + lm * LDP + kst * 32 + lq * 8);
      #pragma unroll
      for (int p = 0; p < 4; ++p)
        acc[p] = __builtin_amdgcn_mfma_f32_16x16x32_bf16(af, bhhf[p][kst], acc[p], 0, 0, 0);
    }
    #pragma unroll
    for (int ks = 0; ks < 3; ++ks) {
      short8 af;
      #pragma unroll
      for (int jj = 0; jj < 8; ++jj) {
        const int kk = ks * 32 + lq * 8 + jj;
        short v = ((kk == xv) || (kk == 64 + av)) ? (short)0x3F80 : (short)0;
        if (kk == 80) v = (short)rwb;
        if (kk == 81) v = (short)dnb;
        af[jj] = v;
      }
      #pragma unroll
      for (int p = 0; p < 4; ++p)
        acc[p] = __builtin_amdgcn_mfma_f32_16x16x32_bf16(af, bihf[p][ks], acc[p], 0, 0, 0);
    }
    short* hw = hbuf[t & 1];
    #pragma unroll
    for (int r = 0; r < 4; ++r) {
      const float iv = acc[0][r] + bs[0], fv = acc[1][r] + bs[1];
      const float gv = acc[2][r] + bs[2], ov = acc[3][r] + bs[3];
      const float c = sigf(fv) * cst[r] + sigf(iv) * tanhf_fast(gv);
      cst[r] = c;
      const float hn = sigf(ov) * tanhf_fast(c);
      hlast[r] = hn;
      const int m = lq * 4 + r;
      out[((size_t)(b0 + m) * Tt + t) * Hh + j] = hn;
      hw[m * LDP + j] = (short)bf16u(hn);
    }
    __syncthreads();
  }
  const size_t base = (size_t)Bb * Tt * Hh;
  #pragma unroll
  for (int r = 0; r < 4; ++r) {
    const int m = lq * 4 + r;
    out[base + (size_t)(b0 + m) * (2 * Hh) + j]      = hlast[r];
    out[base + (size_t)(b0 + m) * (2 * Hh) + Hh + j] = cst[r];
  }
}

}  // namespace

extern "C" void kernel_launch(void* const* d_in, const int* in_sizes, int n_in,
                              void* d_out, int out_size, void* d_ws, size_t ws_size,
                              hipStream_t stream) {
  const int*   xs     = (const int*)  d_in[0];
  const float* hidden = (const float*)d_in[1];
  const int*   pa     = (const int*)  d_in[2];
  const float* prw    = (const float*)d_in[3];
  const float* pdn    = (const float*)d_in[4];
  const float* Wih    = (const float*)d_in[5];
  const float* Whh    = (const float*)d_in[6];
  const float* bih    = (const float*)d_in[7];
  const float* bhh    = (const float*)d_in[8];
  float* out = (float*)d_out;

  if (ws_size >= WS_NEED) {
    unsigned char* ws = (unsigned char*)d_ws;
    const int prepN = (82 * 1024 + 1024 + 2 * 16 * 8 * 64 + 255) / 256;
    prep_kernel<<<dim3(prepN), dim3(256), 0, stream>>>(Wih, Whh, bih, bhh, ws);
    xp_kernel<<<dim3(Tt), dim3(256), 0, stream>>>(xs, pa, prw, pdn, ws);
    lstm_rec<<<dim3(8), dim3(1024), 0, stream>>>(hidden, Whh, ws, out);
  } else {
    lstm_fused<<<dim3(8), dim3(1024), 0, stream>>>(
        xs, hidden, pa, prw, pdn, Wih, Whh, bih, bhh, out);
  }
}